// Round 1
// baseline (4843.631 us; speedup 1.0000x reference)
//
#include <hip/hip_runtime.h>
#include <hip/hip_bf16.h>
#include <math.h>

// Dims: B=16 S=512 D=768 H=12 DH=64 F=3072 LYR=12 NLAB=2; rows = B*S = 8192
typedef __bf16 bf16_t;
typedef __attribute__((ext_vector_type(8))) __bf16 bf16x8;
typedef __attribute__((ext_vector_type(4))) float f32x4;

typedef const __attribute__((address_space(1))) void av1_void;
typedef __attribute__((address_space(3))) void av3_void;

#define DEV static __device__ __forceinline__

DEV void gload16(const void* g, void* l) {
  __builtin_amdgcn_global_load_lds((av1_void*)g, (av3_void*)l, 16, 0, 0);
}

// ---- block reduction over 3 waves (block=192) ----
DEV float bsum3(float v, float* red) {
#pragma unroll
  for (int o = 32; o > 0; o >>= 1) v += __shfl_xor(v, o, 64);
  __syncthreads();
  if ((threadIdx.x & 63) == 0) red[threadIdx.x >> 6] = v;
  __syncthreads();
  return red[0] + red[1] + red[2];
}

// ---- embedding gather + LN -> x (fp32) ----
__global__ __launch_bounds__(192) void k_embed(
    const int* __restrict__ ids, const float* __restrict__ tok,
    const float* __restrict__ pos, const float* __restrict__ gam,
    const float* __restrict__ bet, float* __restrict__ x) {
  __shared__ float red[3];
  int row = blockIdx.x;          // b*512 + s
  int s = row & 511;
  int t = threadIdx.x;
  int id = ids[row];
  const float4 tv = *(const float4*)&tok[(size_t)id * 768 + t * 4];
  const float4 pv = *(const float4*)&pos[(size_t)s * 768 + t * 4];
  float v[4] = {tv.x + pv.x, tv.y + pv.y, tv.z + pv.z, tv.w + pv.w};
  float tot = bsum3(v[0] + v[1] + v[2] + v[3], red);
  float mu = tot * (1.f / 768.f);
  float sq = 0.f;
#pragma unroll
  for (int u = 0; u < 4; ++u) { float d = v[u] - mu; sq += d * d; }
  float var = bsum3(sq, red) * (1.f / 768.f);
  float rstd = rsqrtf(var + 1e-5f);
  const float4 g4 = *(const float4*)&gam[t * 4];
  const float4 b4 = *(const float4*)&bet[t * 4];
  float4 o;
  o.x = (v[0] - mu) * rstd * g4.x + b4.x;
  o.y = (v[1] - mu) * rstd * g4.y + b4.y;
  o.z = (v[2] - mu) * rstd * g4.z + b4.z;
  o.w = (v[3] - mu) * rstd * g4.w + b4.w;
  *(float4*)&x[(size_t)row * 768 + t * 4] = o;
}

// ---- LN: x (fp32) -> h (bf16) ----
__global__ __launch_bounds__(192) void k_ln(
    const float* __restrict__ xin, bf16_t* __restrict__ hout,
    const float* __restrict__ gam, const float* __restrict__ bet) {
  __shared__ float red[3];
  int row = blockIdx.x;
  int t = threadIdx.x;
  const float4 xv = *(const float4*)&xin[(size_t)row * 768 + t * 4];
  float v[4] = {xv.x, xv.y, xv.z, xv.w};
  float tot = bsum3(v[0] + v[1] + v[2] + v[3], red);
  float mu = tot * (1.f / 768.f);
  float sq = 0.f;
#pragma unroll
  for (int u = 0; u < 4; ++u) { float d = v[u] - mu; sq += d * d; }
  float var = bsum3(sq, red) * (1.f / 768.f);
  float rstd = rsqrtf(var + 1e-5f);
  const float4 g4 = *(const float4*)&gam[t * 4];
  const float4 b4 = *(const float4*)&bet[t * 4];
  union { bf16_t o[4]; uint2 u2; } pk;
  pk.o[0] = (bf16_t)((v[0] - mu) * rstd * g4.x + b4.x);
  pk.o[1] = (bf16_t)((v[1] - mu) * rstd * g4.y + b4.y);
  pk.o[2] = (bf16_t)((v[2] - mu) * rstd * g4.z + b4.z);
  pk.o[3] = (bf16_t)((v[3] - mu) * rstd * g4.w + b4.w);
  *(uint2*)&hout[(size_t)row * 768 + t * 4] = pk.u2;
}

// ---- transpose-convert fp32 [K][N] -> bf16 [N][K], per z-slice ----
__global__ __launch_bounds__(256) void k_convT(
    const float* __restrict__ in, size_t in_slice, bf16_t* __restrict__ out,
    size_t out_slice, int N, int K) {
  __shared__ float tbuf[32][33];
  int slice = blockIdx.z;
  const float* ip = in + (size_t)slice * in_slice;
  bf16_t* op = out + (size_t)slice * out_slice;
  int n0 = blockIdx.x * 32, k0 = blockIdx.y * 32;
  int c = threadIdx.x & 31, r8 = threadIdx.x >> 5;
#pragma unroll
  for (int i = 0; i < 4; ++i) {
    int rr = r8 + i * 8;
    tbuf[rr][c] = ip[(size_t)(k0 + rr) * N + n0 + c];
  }
  __syncthreads();
#pragma unroll
  for (int i = 0; i < 4; ++i) {
    int rr = r8 + i * 8;
    op[(size_t)(n0 + rr) * K + k0 + c] = (bf16_t)tbuf[c][rr];
  }
}

// ---- GEMM: C[M,N] = A[M,K] * Bt[N,K]^T   (bf16 in, fp32 acc) ----
// EPI 0: store bf16; EPI 1: Cf += C + bias (fp32 residual); EPI 2: gelu(C+bias) -> bf16
template <int EPI>
__global__ __launch_bounds__(256) void k_gemm(
    const bf16_t* __restrict__ A, int lda, const bf16_t* __restrict__ Bt,
    int ldb, int K, float* __restrict__ Cf, bf16_t* __restrict__ Cb, int ldc,
    const float* __restrict__ bias) {
  __shared__ __attribute__((aligned(16))) bf16_t As[128 * 64];
  __shared__ __attribute__((aligned(16))) bf16_t Bs[128 * 64];
  const int tid = threadIdx.x;
  const int m0 = blockIdx.y * 128, n0 = blockIdx.x * 128;
  const int lane = tid & 63, w = tid >> 6;
  const int wm = w >> 1, wn = w & 1;
  const int r = lane & 15, g4 = lane >> 4;

  f32x4 acc[4][4];
#pragma unroll
  for (int m = 0; m < 4; ++m)
#pragma unroll
    for (int n = 0; n < 4; ++n)
#pragma unroll
      for (int e = 0; e < 4; ++e) acc[m][n][e] = 0.f;

  for (int k0 = 0; k0 < K; k0 += 64) {
#pragma unroll
    for (int i = 0; i < 4; ++i) {
      int c = i * 256 + tid;
      gload16(A + (size_t)(m0 + (c >> 3)) * lda + k0 + (c & 7) * 8,
              (char*)As + (size_t)(i * 256 + (w << 6)) * 16);
    }
#pragma unroll
    for (int i = 0; i < 4; ++i) {
      int c = i * 256 + tid;
      gload16(Bt + (size_t)(n0 + (c >> 3)) * ldb + k0 + (c & 7) * 8,
              (char*)Bs + (size_t)(i * 256 + (w << 6)) * 16);
    }
    __syncthreads();
#pragma unroll
    for (int kk = 0; kk < 2; ++kk) {
      bf16x8 af[4], bfr[4];
#pragma unroll
      for (int m = 0; m < 4; ++m)
        af[m] = *(const bf16x8*)&As[(wm * 64 + m * 16 + r) * 64 + kk * 32 + g4 * 8];
#pragma unroll
      for (int n = 0; n < 4; ++n)
        bfr[n] = *(const bf16x8*)&Bs[(wn * 64 + n * 16 + r) * 64 + kk * 32 + g4 * 8];
#pragma unroll
      for (int m = 0; m < 4; ++m)
#pragma unroll
        for (int n = 0; n < 4; ++n)
          acc[m][n] = __builtin_amdgcn_mfma_f32_16x16x32_bf16(af[m], bfr[n],
                                                              acc[m][n], 0, 0, 0);
    }
    __syncthreads();
  }

#pragma unroll
  for (int m = 0; m < 4; ++m) {
#pragma unroll
    for (int n = 0; n < 4; ++n) {
      int col = n0 + wn * 64 + n * 16 + r;
      float bv = 0.f;
      if constexpr (EPI != 0) bv = bias[col];
#pragma unroll
      for (int j = 0; j < 4; ++j) {
        int row = m0 + wm * 64 + m * 16 + g4 * 4 + j;
        float v = acc[m][n][j];
        if constexpr (EPI == 0) {
          Cb[(size_t)row * ldc + col] = (bf16_t)v;
        } else if constexpr (EPI == 1) {
          size_t o = (size_t)row * ldc + col;
          Cf[o] += v + bv;
        } else {
          float tt = v + bv;
          float ge = 0.5f * tt * (1.f + erff(tt * 0.70710678118f));
          Cb[(size_t)row * ldc + col] = (bf16_t)ge;
        }
      }
    }
  }
}

// ---- lse[b,h,s] = logsumexp_t( q.k/8 ) ; 64 q-rows per block ----
__global__ __launch_bounds__(256) void k_lse(const bf16_t* __restrict__ qkv,
                                             float* __restrict__ lseb) {
  __shared__ __attribute__((aligned(16))) bf16_t Ks[512 * 64];
  __shared__ __attribute__((aligned(16))) bf16_t Qs[64 * 64];
  int bh = blockIdx.x;
  int b = bh / 12, hh = bh % 12;
  int s0 = blockIdx.y * 64;
  int tid = threadIdx.x, lane = tid & 63, w = tid >> 6;
  int r = lane & 15, g4 = lane >> 4;
  const bf16_t* kb = qkv + (size_t)b * 512 * 2304 + 768 + hh * 64;
  const bf16_t* qb = qkv + ((size_t)(b * 512 + s0)) * 2304 + hh * 64;
#pragma unroll
  for (int i = 0; i < 16; ++i) {
    int c = i * 256 + tid;
    gload16(kb + (size_t)(c >> 3) * 2304 + (c & 7) * 8,
            (char*)Ks + (size_t)(i * 256 + (w << 6)) * 16);
  }
#pragma unroll
  for (int i = 0; i < 2; ++i) {
    int c = i * 256 + tid;
    gload16(qb + (size_t)(c >> 3) * 2304 + (c & 7) * 8,
            (char*)Qs + (size_t)(i * 256 + (w << 6)) * 16);
  }
  __syncthreads();

  f32x4 acc[32];
#pragma unroll
  for (int n = 0; n < 32; ++n)
#pragma unroll
    for (int e = 0; e < 4; ++e) acc[n][e] = 0.f;

#pragma unroll
  for (int kk = 0; kk < 2; ++kk) {
    bf16x8 aq = *(const bf16x8*)&Qs[(w * 16 + r) * 64 + kk * 32 + g4 * 8];
#pragma unroll
    for (int n = 0; n < 32; ++n) {
      bf16x8 bk = *(const bf16x8*)&Ks[(n * 16 + r) * 64 + kk * 32 + g4 * 8];
      acc[n] = __builtin_amdgcn_mfma_f32_16x16x32_bf16(aq, bk, acc[n], 0, 0, 0);
    }
  }
#pragma unroll
  for (int j = 0; j < 4; ++j) {
    float mx = -1e30f;
#pragma unroll
    for (int n = 0; n < 32; ++n) mx = fmaxf(mx, acc[n][j] * 0.125f);
#pragma unroll
    for (int o = 1; o < 16; o <<= 1) mx = fmaxf(mx, __shfl_xor(mx, o, 64));
    float sm = 0.f;
#pragma unroll
    for (int n = 0; n < 32; ++n) sm += expf(acc[n][j] * 0.125f - mx);
#pragma unroll
    for (int o = 1; o < 16; o <<= 1) sm += __shfl_xor(sm, o, 64);
    if (r == 0)
      lseb[(size_t)bh * 512 + s0 + w * 16 + g4 * 4 + j] = mx + logf(sm);
  }
}

// ---- M[b,h] = K^T V / 8 (64x64) and sumv[b,h] = sum_t V ----
__global__ __launch_bounds__(256) void k_msumv(const bf16_t* __restrict__ qkv,
                                               float* __restrict__ Mb,
                                               float* __restrict__ sumv) {
  __shared__ __attribute__((aligned(16))) bf16_t Ks[128 * 64];
  __shared__ __attribute__((aligned(16))) float Vs[128 * 64];
  int bh = blockIdx.x;
  int b = bh / 12, hh = bh % 12;
  const bf16_t* kb = qkv + (size_t)b * 512 * 2304 + 768 + hh * 64;
  const bf16_t* vb = qkv + (size_t)b * 512 * 2304 + 1536 + hh * 64;
  int tid = threadIdx.x;
  int e1 = tid & 63, grp = tid >> 6;
  f32x4 macc[4];
#pragma unroll
  for (int jj = 0; jj < 4; ++jj)
#pragma unroll
    for (int e = 0; e < 4; ++e) macc[jj][e] = 0.f;
  float sv = 0.f;

  for (int t0 = 0; t0 < 512; t0 += 128) {
#pragma unroll
    for (int i = 0; i < 4; ++i) {
      int c = i * 256 + tid;
      gload16(kb + (size_t)(t0 + (c >> 3)) * 2304 + (c & 7) * 8,
              (char*)Ks + (size_t)(i * 256 + (grp << 6)) * 16);
    }
#pragma unroll
    for (int i = 0; i < 4; ++i) {
      int c = i * 256 + tid;
      int row = c >> 3, col = (c & 7) * 8;
      bf16x8 raw = *(const bf16x8*)(vb + (size_t)(t0 + row) * 2304 + col);
      f32x4 v0, v1;
#pragma unroll
      for (int u = 0; u < 4; ++u) { v0[u] = (float)raw[u]; v1[u] = (float)raw[u + 4]; }
      *(f32x4*)&Vs[row * 64 + col] = v0;
      *(f32x4*)&Vs[row * 64 + col + 4] = v1;
    }
    __syncthreads();
    for (int tt = 0; tt < 128; ++tt) {
      float kv = (float)Ks[tt * 64 + e1];
#pragma unroll
      for (int jj = 0; jj < 4; ++jj) {
        f32x4 vv = *(const f32x4*)&Vs[tt * 64 + grp * 16 + jj * 4];
        macc[jj] += kv * vv;
      }
    }
    if (tid < 64) {
      for (int tt = 0; tt < 128; ++tt) sv += Vs[tt * 64 + tid];
    }
    __syncthreads();
  }
#pragma unroll
  for (int jj = 0; jj < 4; ++jj)
#pragma unroll
    for (int u = 0; u < 4; ++u)
      Mb[(size_t)bh * 4096 + e1 * 64 + grp * 16 + jj * 4 + u] =
          macc[jj][u] * 0.125f;
  if (tid < 64) sumv[(size_t)bh * 64 + tid] = sv;
}

// ---- ctx[b,s,h*64+e2] = q[s,:].M[:,e2] - lse[s]*sumv[e2]  (bf16 out) ----
__global__ __launch_bounds__(256) void k_ctx(
    const bf16_t* __restrict__ qkv, const float* __restrict__ Mb,
    const float* __restrict__ sumv, const float* __restrict__ lseb,
    bf16_t* __restrict__ ctx) {
  __shared__ __attribute__((aligned(16))) bf16_t Qs[512 * 64];
  __shared__ __attribute__((aligned(16))) bf16_t Mt[64 * 64];
  int bh = blockIdx.x;
  int b = bh / 12, hh = bh % 12;
  int tid = threadIdx.x, lane = tid & 63, w = tid >> 6;
  int r = lane & 15, g4 = lane >> 4;
  const bf16_t* qb = qkv + (size_t)b * 512 * 2304 + hh * 64;
#pragma unroll
  for (int i = 0; i < 16; ++i) {
    int c = i * 256 + tid;
    gload16(qb + (size_t)(c >> 3) * 2304 + (c & 7) * 8,
            (char*)Qs + (size_t)(i * 256 + (w << 6)) * 16);
  }
  const float* Mp = Mb + (size_t)bh * 4096;
#pragma unroll
  for (int i = 0; i < 16; ++i) {
    int idx = i * 256 + tid;
    int ee1 = idx >> 6, ee2 = idx & 63;
    Mt[ee2 * 64 + ee1] = (bf16_t)Mp[idx];
  }
  __syncthreads();

  f32x4 acc[8][4];
#pragma unroll
  for (int m = 0; m < 8; ++m)
#pragma unroll
    for (int n = 0; n < 4; ++n)
#pragma unroll
      for (int e = 0; e < 4; ++e) acc[m][n][e] = 0.f;

#pragma unroll
  for (int kk = 0; kk < 2; ++kk) {
    bf16x8 bm[4];
#pragma unroll
    for (int n = 0; n < 4; ++n)
      bm[n] = *(const bf16x8*)&Mt[(n * 16 + r) * 64 + kk * 32 + g4 * 8];
#pragma unroll
    for (int m = 0; m < 8; ++m) {
      bf16x8 aq = *(const bf16x8*)&Qs[(w * 128 + m * 16 + r) * 64 + kk * 32 + g4 * 8];
#pragma unroll
      for (int n = 0; n < 4; ++n)
        acc[m][n] = __builtin_amdgcn_mfma_f32_16x16x32_bf16(aq, bm[n], acc[m][n], 0, 0, 0);
    }
  }
#pragma unroll
  for (int m = 0; m < 8; ++m) {
#pragma unroll
    for (int n = 0; n < 4; ++n) {
      int col = n * 16 + r;
      float svv = sumv[(size_t)bh * 64 + col];
#pragma unroll
      for (int j = 0; j < 4; ++j) {
        int s = w * 128 + m * 16 + g4 * 4 + j;
        float lv = lseb[(size_t)bh * 512 + s];
        float val = acc[m][n][j] - lv * svv;
        ctx[((size_t)(b * 512 + s)) * 768 + hh * 64 + col] = (bf16_t)val;
      }
    }
  }
}

// ---- final LN (row s=0 per batch) + classifier ----
__global__ __launch_bounds__(192) void k_final(
    const float* __restrict__ x, const float* __restrict__ gam,
    const float* __restrict__ bet, const float* __restrict__ cw,
    const float* __restrict__ cb, float* __restrict__ out) {
  __shared__ float red[3];
  int b = blockIdx.x, t = threadIdx.x;
  const float* xr = x + (size_t)b * 512 * 768;
  const float4 xv = *(const float4*)&xr[t * 4];
  float v[4] = {xv.x, xv.y, xv.z, xv.w};
  float tot = bsum3(v[0] + v[1] + v[2] + v[3], red);
  float mu = tot * (1.f / 768.f);
  float sq = 0.f;
#pragma unroll
  for (int u = 0; u < 4; ++u) { float d = v[u] - mu; sq += d * d; }
  float var = bsum3(sq, red) * (1.f / 768.f);
  float rstd = rsqrtf(var + 1e-5f);
  const float4 g4 = *(const float4*)&gam[t * 4];
  const float4 b4 = *(const float4*)&bet[t * 4];
  float nv[4];
  nv[0] = (v[0] - mu) * rstd * g4.x + b4.x;
  nv[1] = (v[1] - mu) * rstd * g4.y + b4.y;
  nv[2] = (v[2] - mu) * rstd * g4.z + b4.z;
  nv[3] = (v[3] - mu) * rstd * g4.w + b4.w;
  const float4 wa = *(const float4*)&cw[t * 8];
  const float4 wb = *(const float4*)&cw[t * 8 + 4];
  float d0 = nv[0] * wa.x + nv[1] * wa.z + nv[2] * wb.x + nv[3] * wb.z;
  float d1 = nv[0] * wa.y + nv[1] * wa.w + nv[2] * wb.y + nv[3] * wb.w;
  d0 = bsum3(d0, red);
  d1 = bsum3(d1, red);
  if (t == 0) {
    out[b * 2 + 0] = d0 + cb[0];
    out[b * 2 + 1] = d1 + cb[1];
  }
}

// ---- workspace layout ----
static constexpr size_t OFF_X = 0;                                  // f32 8192x768
static constexpr size_t OFF_H = OFF_X + 8192ull * 768 * 4;          // bf16 8192x768
static constexpr size_t OFF_QG = OFF_H + 8192ull * 768 * 2;         // bf16 arena (qkv 8192x2304 | gelu 8192x3072)
static constexpr size_t OFF_CTX = OFF_QG + 8192ull * 3072 * 2;      // bf16 8192x768
static constexpr size_t OFF_W = OFF_CTX + 8192ull * 768 * 2;        // bf16 7077888
static constexpr size_t OFF_LSE = OFF_W + 7077888ull * 2;           // f32 192*512
static constexpr size_t OFF_SV = OFF_LSE + 192ull * 512 * 4;        // f32 192*64
static constexpr size_t OFF_M = OFF_SV + 192ull * 64 * 4;           // f32 192*64*64
static constexpr size_t WS_NEED = OFF_M + 192ull * 64 * 64 * 4;

extern "C" void kernel_launch(void* const* d_in, const int* in_sizes, int n_in,
                              void* d_out, int out_size, void* d_ws,
                              size_t ws_size, hipStream_t stream) {
  const int* ids = (const int*)d_in[0];
  const float* tok = (const float*)d_in[1];
  const float* pos = (const float*)d_in[2];
  const float* eln_s = (const float*)d_in[3];
  const float* eln_b = (const float*)d_in[4];
  const float* wq = (const float*)d_in[5];
  const float* wk = (const float*)d_in[6];
  const float* wv = (const float*)d_in[7];
  const float* wo = (const float*)d_in[8];
  const float* wo_b = (const float*)d_in[9];
  const float* ln1_s = (const float*)d_in[10];
  const float* ln1_b = (const float*)d_in[11];
  const float* ln2_s = (const float*)d_in[12];
  const float* ln2_b = (const float*)d_in[13];
  const float* ff1w = (const float*)d_in[14];
  const float* ff1b = (const float*)d_in[15];
  const float* ff2w = (const float*)d_in[16];
  const float* ff2b = (const float*)d_in[17];
  const float* fln_s = (const float*)d_in[18];
  const float* fln_b = (const float*)d_in[19];
  const float* cw = (const float*)d_in[20];
  const float* cb = (const float*)d_in[21];
  float* out = (float*)d_out;

  if (ws_size < WS_NEED) return;  // workspace too small; will fail validation loudly

  char* ws = (char*)d_ws;
  float* x = (float*)(ws + OFF_X);
  bf16_t* h = (bf16_t*)(ws + OFF_H);
  bf16_t* qkv = (bf16_t*)(ws + OFF_QG);
  bf16_t* gbuf = (bf16_t*)(ws + OFF_QG);
  bf16_t* ctx = (bf16_t*)(ws + OFF_CTX);
  bf16_t* wT = (bf16_t*)(ws + OFF_W);
  float* lseb = (float*)(ws + OFF_LSE);
  float* sv = (float*)(ws + OFF_SV);
  float* Mb = (float*)(ws + OFF_M);

  bf16_t* qkvT = wT;                  // [2304][768]
  bf16_t* woT = wT + 1769472;         // [768][768]
  bf16_t* ff1T = wT + 2359296;        // [3072][768]
  bf16_t* ff2T = wT + 4718592;        // [768][3072]

  k_embed<<<8192, 192, 0, stream>>>(ids, tok, pos, eln_s, eln_b, x);

  for (int l = 0; l < 12; ++l) {
    k_ln<<<8192, 192, 0, stream>>>(x, h, ln1_s + l * 768, ln1_b + l * 768);
    // weight convert+transpose (per layer, reused buffers)
    k_convT<<<dim3(2, 24, 12), 256, 0, stream>>>(wq + (size_t)l * 12 * 768 * 64,
                                                 768 * 64, qkvT, (size_t)64 * 768, 64, 768);
    k_convT<<<dim3(2, 24, 12), 256, 0, stream>>>(wk + (size_t)l * 12 * 768 * 64,
                                                 768 * 64, qkvT + 768 * 768, (size_t)64 * 768, 64, 768);
    k_convT<<<dim3(2, 24, 12), 256, 0, stream>>>(wv + (size_t)l * 12 * 768 * 64,
                                                 768 * 64, qkvT + 1536 * 768, (size_t)64 * 768, 64, 768);
    k_convT<<<dim3(24, 24, 1), 256, 0, stream>>>(wo + (size_t)l * 768 * 768, 0,
                                                 woT, 0, 768, 768);
    k_convT<<<dim3(96, 24, 1), 256, 0, stream>>>(ff1w + (size_t)l * 768 * 3072, 0,
                                                 ff1T, 0, 3072, 768);
    k_convT<<<dim3(24, 96, 1), 256, 0, stream>>>(ff2w + (size_t)l * 3072 * 768, 0,
                                                 ff2T, 0, 768, 3072);
    // QKV projection
    k_gemm<0><<<dim3(18, 64), 256, 0, stream>>>(h, 768, qkvT, 768, 768, nullptr,
                                                qkv, 2304, nullptr);
    // attention (log-softmax decomposition)
    k_lse<<<dim3(192, 8), 256, 0, stream>>>(qkv, lseb);
    k_msumv<<<192, 256, 0, stream>>>(qkv, Mb, sv);
    k_ctx<<<192, 256, 0, stream>>>(qkv, Mb, sv, lseb, ctx);
    // output projection + residual
    k_gemm<1><<<dim3(6, 64), 256, 0, stream>>>(ctx, 768, woT, 768, 768, x,
                                               nullptr, 768, wo_b + l * 768);
    // FFN
    k_ln<<<8192, 192, 0, stream>>>(x, h, ln2_s + l * 768, ln2_b + l * 768);
    k_gemm<2><<<dim3(24, 64), 256, 0, stream>>>(h, 768, ff1T, 768, 768, nullptr,
                                                gbuf, 3072, ff1b + l * 3072);
    k_gemm<1><<<dim3(6, 64), 256, 0, stream>>>(gbuf, 3072, ff2T, 3072, 3072, x,
                                               nullptr, 768, ff2b + l * 768);
  }
  k_final<<<16, 192, 0, stream>>>(x, fln_s, fln_b, cw, cb, out);
}

// Round 2
// 4722.703 us; speedup vs baseline: 1.0256x; 1.0256x over previous
//
#include <hip/hip_runtime.h>
#include <hip/hip_bf16.h>
#include <math.h>

// Dims: B=16 S=512 D=768 H=12 DH=64 F=3072 LYR=12 NLAB=2; rows = B*S = 8192
typedef __bf16 bf16_t;
typedef __attribute__((ext_vector_type(8))) __bf16 bf16x8;
typedef __attribute__((ext_vector_type(4))) float f32x4;

typedef const __attribute__((address_space(1))) void av1_void;
typedef __attribute__((address_space(3))) void av3_void;

#define DEV static __device__ __forceinline__

DEV void gload16(const void* g, void* l) {
  __builtin_amdgcn_global_load_lds((av1_void*)g, (av3_void*)l, 16, 0, 0);
}

// ---- block reduction over 3 waves (block=192) ----
DEV float bsum3(float v, float* red) {
#pragma unroll
  for (int o = 32; o > 0; o >>= 1) v += __shfl_xor(v, o, 64);
  __syncthreads();
  if ((threadIdx.x & 63) == 0) red[threadIdx.x >> 6] = v;
  __syncthreads();
  return red[0] + red[1] + red[2];
}

// ---- embedding gather + LN -> x (fp32) ----
__global__ __launch_bounds__(192) void k_embed(
    const int* __restrict__ ids, const float* __restrict__ tok,
    const float* __restrict__ pos, const float* __restrict__ gam,
    const float* __restrict__ bet, float* __restrict__ x) {
  __shared__ float red[3];
  int row = blockIdx.x;          // b*512 + s
  int s = row & 511;
  int t = threadIdx.x;
  int id = ids[row];
  const float4 tv = *(const float4*)&tok[(size_t)id * 768 + t * 4];
  const float4 pv = *(const float4*)&pos[(size_t)s * 768 + t * 4];
  float v[4] = {tv.x + pv.x, tv.y + pv.y, tv.z + pv.z, tv.w + pv.w};
  float tot = bsum3(v[0] + v[1] + v[2] + v[3], red);
  float mu = tot * (1.f / 768.f);
  float sq = 0.f;
#pragma unroll
  for (int u = 0; u < 4; ++u) { float d = v[u] - mu; sq += d * d; }
  float var = bsum3(sq, red) * (1.f / 768.f);
  float rstd = rsqrtf(var + 1e-5f);
  const float4 g4 = *(const float4*)&gam[t * 4];
  const float4 b4 = *(const float4*)&bet[t * 4];
  float4 o;
  o.x = (v[0] - mu) * rstd * g4.x + b4.x;
  o.y = (v[1] - mu) * rstd * g4.y + b4.y;
  o.z = (v[2] - mu) * rstd * g4.z + b4.z;
  o.w = (v[3] - mu) * rstd * g4.w + b4.w;
  *(float4*)&x[(size_t)row * 768 + t * 4] = o;
}

// ---- LN: x (fp32) -> h (bf16) ----
__global__ __launch_bounds__(192) void k_ln(
    const float* __restrict__ xin, bf16_t* __restrict__ hout,
    const float* __restrict__ gam, const float* __restrict__ bet) {
  __shared__ float red[3];
  int row = blockIdx.x;
  int t = threadIdx.x;
  const float4 xv = *(const float4*)&xin[(size_t)row * 768 + t * 4];
  float v[4] = {xv.x, xv.y, xv.z, xv.w};
  float tot = bsum3(v[0] + v[1] + v[2] + v[3], red);
  float mu = tot * (1.f / 768.f);
  float sq = 0.f;
#pragma unroll
  for (int u = 0; u < 4; ++u) { float d = v[u] - mu; sq += d * d; }
  float var = bsum3(sq, red) * (1.f / 768.f);
  float rstd = rsqrtf(var + 1e-5f);
  const float4 g4 = *(const float4*)&gam[t * 4];
  const float4 b4 = *(const float4*)&bet[t * 4];
  union { bf16_t o[4]; uint2 u2; } pk;
  pk.o[0] = (bf16_t)((v[0] - mu) * rstd * g4.x + b4.x);
  pk.o[1] = (bf16_t)((v[1] - mu) * rstd * g4.y + b4.y);
  pk.o[2] = (bf16_t)((v[2] - mu) * rstd * g4.z + b4.z);
  pk.o[3] = (bf16_t)((v[3] - mu) * rstd * g4.w + b4.w);
  *(uint2*)&hout[(size_t)row * 768 + t * 4] = pk.u2;
}

// ---- transpose-convert fp32 [K][N] -> bf16 [N][K], per z-slice ----
__global__ __launch_bounds__(256) void k_convT(
    const float* __restrict__ in, size_t in_slice, bf16_t* __restrict__ out,
    size_t out_slice, int N, int K) {
  __shared__ float tbuf[32][33];
  int slice = blockIdx.z;
  const float* ip = in + (size_t)slice * in_slice;
  bf16_t* op = out + (size_t)slice * out_slice;
  int n0 = blockIdx.x * 32, k0 = blockIdx.y * 32;
  int c = threadIdx.x & 31, r8 = threadIdx.x >> 5;
#pragma unroll
  for (int i = 0; i < 4; ++i) {
    int rr = r8 + i * 8;
    tbuf[rr][c] = ip[(size_t)(k0 + rr) * N + n0 + c];
  }
  __syncthreads();
#pragma unroll
  for (int i = 0; i < 4; ++i) {
    int rr = r8 + i * 8;
    op[(size_t)(n0 + rr) * K + k0 + c] = (bf16_t)tbuf[c][rr];
  }
}

// ---- GEMM: C[M,N] = A[M,K] * Bt[N,K]^T   (bf16 in, fp32 acc) ----
// 128x128 tile, BK=64, double-buffered LDS, single barrier per K-step,
// both-sides XOR swizzle (linear LDS dest for global_load_lds, inverse-swz
// global source, swz ds_read).
// EPI 0: store bf16; EPI 1: Cf += C + bias (fp32 residual); EPI 2: gelu(C+bias) -> bf16
template <int EPI>
__global__ __launch_bounds__(256) void k_gemm(
    const bf16_t* __restrict__ A, int lda, const bf16_t* __restrict__ Bt,
    int ldb, int K, float* __restrict__ Cf, bf16_t* __restrict__ Cb, int ldc,
    const float* __restrict__ bias) {
  __shared__ __attribute__((aligned(16))) bf16_t As[2][128 * 64];
  __shared__ __attribute__((aligned(16))) bf16_t Bs[2][128 * 64];
  const int tid = threadIdx.x;
  const int m0 = blockIdx.y * 128, n0 = blockIdx.x * 128;
  const int lane = tid & 63, w = tid >> 6;
  const int wm = w >> 1, wn = w & 1;
  const int r = lane & 15, g4 = lane >> 4;

  f32x4 acc[4][4];
#pragma unroll
  for (int m = 0; m < 4; ++m)
#pragma unroll
    for (int n = 0; n < 4; ++n)
#pragma unroll
      for (int e = 0; e < 4; ++e) acc[m][n][e] = 0.f;

  // stage one 64-wide K-tile into buffer `buf`; LDS dest linear, global
  // source chunk index XOR-swizzled so that swizzled reads see the right data
  auto STAGE = [&](int buf, int k0) {
#pragma unroll
    for (int i = 0; i < 4; ++i) {
      int s = i * 256 + tid;           // 16B slot index in [128][8]
      int row = s >> 3;
      int c = (s & 7) ^ (row & 7);     // source chunk for this slot
      gload16(A + (size_t)(m0 + row) * lda + k0 + c * 8,
              (char*)&As[buf][0] + (size_t)(i * 256 + (w << 6)) * 16);
    }
#pragma unroll
    for (int i = 0; i < 4; ++i) {
      int s = i * 256 + tid;
      int row = s >> 3;
      int c = (s & 7) ^ (row & 7);
      gload16(Bt + (size_t)(n0 + row) * ldb + k0 + c * 8,
              (char*)&Bs[buf][0] + (size_t)(i * 256 + (w << 6)) * 16);
    }
  };

  auto COMPUTE = [&](int buf) {
#pragma unroll
    for (int kk = 0; kk < 2; ++kk) {
      bf16x8 af[4], bb[4];
#pragma unroll
      for (int m = 0; m < 4; ++m) {
        int row = wm * 64 + m * 16 + r;
        af[m] = *(const bf16x8*)&As[buf][row * 64 +
                                        (((kk << 2) + g4) ^ (row & 7)) * 8];
      }
#pragma unroll
      for (int n = 0; n < 4; ++n) {
        int row = wn * 64 + n * 16 + r;
        bb[n] = *(const bf16x8*)&Bs[buf][row * 64 +
                                         (((kk << 2) + g4) ^ (row & 7)) * 8];
      }
#pragma unroll
      for (int m = 0; m < 4; ++m)
#pragma unroll
        for (int n = 0; n < 4; ++n)
          acc[m][n] = __builtin_amdgcn_mfma_f32_16x16x32_bf16(af[m], bb[n],
                                                              acc[m][n], 0, 0, 0);
    }
  };

  const int nt = K >> 6;
  STAGE(0, 0);
  __syncthreads();               // drains vmcnt(0): buf0 ready
  int cur = 0;
  for (int t = 0; t < nt - 1; ++t) {
    STAGE(cur ^ 1, (t + 1) << 6);  // issue next tile; in flight during compute
    COMPUTE(cur);
    __syncthreads();             // drains vmcnt(0)+lgkmcnt(0): next buf ready,
    cur ^= 1;                    // and everyone done reading old buf
  }
  COMPUTE(cur);

#pragma unroll
  for (int m = 0; m < 4; ++m) {
#pragma unroll
    for (int n = 0; n < 4; ++n) {
      int col = n0 + wn * 64 + n * 16 + r;
      float bv = 0.f;
      if constexpr (EPI != 0) bv = bias[col];
#pragma unroll
      for (int j = 0; j < 4; ++j) {
        int row = m0 + wm * 64 + m * 16 + g4 * 4 + j;
        float v = acc[m][n][j];
        if constexpr (EPI == 0) {
          Cb[(size_t)row * ldc + col] = (bf16_t)v;
        } else if constexpr (EPI == 1) {
          size_t o = (size_t)row * ldc + col;
          Cf[o] += v + bv;
        } else {
          float tt = v + bv;
          float ge = 0.5f * tt * (1.f + erff(tt * 0.70710678118f));
          Cb[(size_t)row * ldc + col] = (bf16_t)ge;
        }
      }
    }
  }
}

// ---- lse[b,h,s] = logsumexp_t( q.k/8 ) ; 64 q-rows per block ----
__global__ __launch_bounds__(256) void k_lse(const bf16_t* __restrict__ qkv,
                                             float* __restrict__ lseb) {
  __shared__ __attribute__((aligned(16))) bf16_t Ks[512 * 64];
  __shared__ __attribute__((aligned(16))) bf16_t Qs[64 * 64];
  int bh = blockIdx.x;
  int b = bh / 12, hh = bh % 12;
  int s0 = blockIdx.y * 64;
  int tid = threadIdx.x, lane = tid & 63, w = tid >> 6;
  int r = lane & 15, g4 = lane >> 4;
  const bf16_t* kb = qkv + (size_t)b * 512 * 2304 + 768 + hh * 64;
  const bf16_t* qb = qkv + ((size_t)(b * 512 + s0)) * 2304 + hh * 64;
#pragma unroll
  for (int i = 0; i < 16; ++i) {
    int c = i * 256 + tid;
    gload16(kb + (size_t)(c >> 3) * 2304 + (c & 7) * 8,
            (char*)Ks + (size_t)(i * 256 + (w << 6)) * 16);
  }
#pragma unroll
  for (int i = 0; i < 2; ++i) {
    int c = i * 256 + tid;
    gload16(qb + (size_t)(c >> 3) * 2304 + (c & 7) * 8,
            (char*)Qs + (size_t)(i * 256 + (w << 6)) * 16);
  }
  __syncthreads();

  f32x4 acc[32];
#pragma unroll
  for (int n = 0; n < 32; ++n)
#pragma unroll
    for (int e = 0; e < 4; ++e) acc[n][e] = 0.f;

#pragma unroll
  for (int kk = 0; kk < 2; ++kk) {
    bf16x8 aq = *(const bf16x8*)&Qs[(w * 16 + r) * 64 + kk * 32 + g4 * 8];
#pragma unroll
    for (int n = 0; n < 32; ++n) {
      bf16x8 bk = *(const bf16x8*)&Ks[(n * 16 + r) * 64 + kk * 32 + g4 * 8];
      acc[n] = __builtin_amdgcn_mfma_f32_16x16x32_bf16(aq, bk, acc[n], 0, 0, 0);
    }
  }
#pragma unroll
  for (int j = 0; j < 4; ++j) {
    float mx = -1e30f;
#pragma unroll
    for (int n = 0; n < 32; ++n) mx = fmaxf(mx, acc[n][j] * 0.125f);
#pragma unroll
    for (int o = 1; o < 16; o <<= 1) mx = fmaxf(mx, __shfl_xor(mx, o, 64));
    float sm = 0.f;
#pragma unroll
    for (int n = 0; n < 32; ++n) sm += expf(acc[n][j] * 0.125f - mx);
#pragma unroll
    for (int o = 1; o < 16; o <<= 1) sm += __shfl_xor(sm, o, 64);
    if (r == 0)
      lseb[(size_t)bh * 512 + s0 + w * 16 + g4 * 4 + j] = mx + logf(sm);
  }
}

// ---- M[b,h] = K^T V / 8 (64x64) and sumv[b,h] = sum_t V ----
__global__ __launch_bounds__(256) void k_msumv(const bf16_t* __restrict__ qkv,
                                               float* __restrict__ Mb,
                                               float* __restrict__ sumv) {
  __shared__ __attribute__((aligned(16))) bf16_t Ks[128 * 64];
  __shared__ __attribute__((aligned(16))) float Vs[128 * 64];
  int bh = blockIdx.x;
  int b = bh / 12, hh = bh % 12;
  const bf16_t* kb = qkv + (size_t)b * 512 * 2304 + 768 + hh * 64;
  const bf16_t* vb = qkv + (size_t)b * 512 * 2304 + 1536 + hh * 64;
  int tid = threadIdx.x;
  int e1 = tid & 63, grp = tid >> 6;
  f32x4 macc[4];
#pragma unroll
  for (int jj = 0; jj < 4; ++jj)
#pragma unroll
    for (int e = 0; e < 4; ++e) macc[jj][e] = 0.f;
  float sv = 0.f;

  for (int t0 = 0; t0 < 512; t0 += 128) {
#pragma unroll
    for (int i = 0; i < 4; ++i) {
      int c = i * 256 + tid;
      gload16(kb + (size_t)(t0 + (c >> 3)) * 2304 + (c & 7) * 8,
              (char*)Ks + (size_t)(i * 256 + (grp << 6)) * 16);
    }
#pragma unroll
    for (int i = 0; i < 4; ++i) {
      int c = i * 256 + tid;
      int row = c >> 3, col = (c & 7) * 8;
      bf16x8 raw = *(const bf16x8*)(vb + (size_t)(t0 + row) * 2304 + col);
      f32x4 v0, v1;
#pragma unroll
      for (int u = 0; u < 4; ++u) { v0[u] = (float)raw[u]; v1[u] = (float)raw[u + 4]; }
      *(f32x4*)&Vs[row * 64 + col] = v0;
      *(f32x4*)&Vs[row * 64 + col + 4] = v1;
    }
    __syncthreads();
    for (int tt = 0; tt < 128; ++tt) {
      float kv = (float)Ks[tt * 64 + e1];
#pragma unroll
      for (int jj = 0; jj < 4; ++jj) {
        f32x4 vv = *(const f32x4*)&Vs[tt * 64 + grp * 16 + jj * 4];
        macc[jj] += kv * vv;
      }
    }
    if (tid < 64) {
      for (int tt = 0; tt < 128; ++tt) sv += Vs[tt * 64 + tid];
    }
    __syncthreads();
  }
#pragma unroll
  for (int jj = 0; jj < 4; ++jj)
#pragma unroll
    for (int u = 0; u < 4; ++u)
      Mb[(size_t)bh * 4096 + e1 * 64 + grp * 16 + jj * 4 + u] =
          macc[jj][u] * 0.125f;
  if (tid < 64) sumv[(size_t)bh * 64 + tid] = sv;
}

// ---- ctx[b,s,h*64+e2] = q[s,:].M[:,e2] - lse[s]*sumv[e2]  (bf16 out) ----
__global__ __launch_bounds__(256) void k_ctx(
    const bf16_t* __restrict__ qkv, const float* __restrict__ Mb,
    const float* __restrict__ sumv, const float* __restrict__ lseb,
    bf16_t* __restrict__ ctx) {
  __shared__ __attribute__((aligned(16))) bf16_t Qs[512 * 64];
  __shared__ __attribute__((aligned(16))) bf16_t Mt[64 * 64];
  int bh = blockIdx.x;
  int b = bh / 12, hh = bh % 12;
  int tid = threadIdx.x, lane = tid & 63, w = tid >> 6;
  int r = lane & 15, g4 = lane >> 4;
  const bf16_t* qb = qkv + (size_t)b * 512 * 2304 + hh * 64;
#pragma unroll
  for (int i = 0; i < 16; ++i) {
    int c = i * 256 + tid;
    gload16(qb + (size_t)(c >> 3) * 2304 + (c & 7) * 8,
            (char*)Qs + (size_t)(i * 256 + (w << 6)) * 16);
  }
  const float* Mp = Mb + (size_t)bh * 4096;
#pragma unroll
  for (int i = 0; i < 16; ++i) {
    int idx = i * 256 + tid;
    int ee1 = idx >> 6, ee2 = idx & 63;
    Mt[ee2 * 64 + ee1] = (bf16_t)Mp[idx];
  }
  __syncthreads();

  f32x4 acc[8][4];
#pragma unroll
  for (int m = 0; m < 8; ++m)
#pragma unroll
    for (int n = 0; n < 4; ++n)
#pragma unroll
      for (int e = 0; e < 4; ++e) acc[m][n][e] = 0.f;

#pragma unroll
  for (int kk = 0; kk < 2; ++kk) {
    bf16x8 bm[4];
#pragma unroll
    for (int n = 0; n < 4; ++n)
      bm[n] = *(const bf16x8*)&Mt[(n * 16 + r) * 64 + kk * 32 + g4 * 8];
#pragma unroll
    for (int m = 0; m < 8; ++m) {
      bf16x8 aq = *(const bf16x8*)&Qs[(w * 128 + m * 16 + r) * 64 + kk * 32 + g4 * 8];
#pragma unroll
      for (int n = 0; n < 4; ++n)
        acc[m][n] = __builtin_amdgcn_mfma_f32_16x16x32_bf16(aq, bm[n], acc[m][n], 0, 0, 0);
    }
  }
#pragma unroll
  for (int m = 0; m < 8; ++m) {
#pragma unroll
    for (int n = 0; n < 4; ++n) {
      int col = n * 16 + r;
      float svv = sumv[(size_t)bh * 64 + col];
#pragma unroll
      for (int j = 0; j < 4; ++j) {
        int s = w * 128 + m * 16 + g4 * 4 + j;
        float lv = lseb[(size_t)bh * 512 + s];
        float val = acc[m][n][j] - lv * svv;
        ctx[((size_t)(b * 512 + s)) * 768 + hh * 64 + col] = (bf16_t)val;
      }
    }
  }
}

// ---- final LN (row s=0 per batch) + classifier ----
__global__ __launch_bounds__(192) void k_final(
    const float* __restrict__ x, const float* __restrict__ gam,
    const float* __restrict__ bet, const float* __restrict__ cw,
    const float* __restrict__ cb, float* __restrict__ out) {
  __shared__ float red[3];
  int b = blockIdx.x, t = threadIdx.x;
  const float* xr = x + (size_t)b * 512 * 768;
  const float4 xv = *(const float4*)&xr[t * 4];
  float v[4] = {xv.x, xv.y, xv.z, xv.w};
  float tot = bsum3(v[0] + v[1] + v[2] + v[3], red);
  float mu = tot * (1.f / 768.f);
  float sq = 0.f;
#pragma unroll
  for (int u = 0; u < 4; ++u) { float d = v[u] - mu; sq += d * d; }
  float var = bsum3(sq, red) * (1.f / 768.f);
  float rstd = rsqrtf(var + 1e-5f);
  const float4 g4 = *(const float4*)&gam[t * 4];
  const float4 b4 = *(const float4*)&bet[t * 4];
  float nv[4];
  nv[0] = (v[0] - mu) * rstd * g4.x + b4.x;
  nv[1] = (v[1] - mu) * rstd * g4.y + b4.y;
  nv[2] = (v[2] - mu) * rstd * g4.z + b4.z;
  nv[3] = (v[3] - mu) * rstd * g4.w + b4.w;
  const float4 wa = *(const float4*)&cw[t * 8];
  const float4 wb = *(const float4*)&cw[t * 8 + 4];
  float d0 = nv[0] * wa.x + nv[1] * wa.z + nv[2] * wb.x + nv[3] * wb.z;
  float d1 = nv[0] * wa.y + nv[1] * wa.w + nv[2] * wb.y + nv[3] * wb.w;
  d0 = bsum3(d0, red);
  d1 = bsum3(d1, red);
  if (t == 0) {
    out[b * 2 + 0] = d0 + cb[0];
    out[b * 2 + 1] = d1 + cb[1];
  }
}

// ---- workspace layout ----
static constexpr size_t OFF_X = 0;                                  // f32 8192x768
static constexpr size_t OFF_H = OFF_X + 8192ull * 768 * 4;          // bf16 8192x768
static constexpr size_t OFF_QG = OFF_H + 8192ull * 768 * 2;         // bf16 arena (qkv 8192x2304 | gelu 8192x3072)
static constexpr size_t OFF_CTX = OFF_QG + 8192ull * 3072 * 2;      // bf16 8192x768
static constexpr size_t OFF_W = OFF_CTX + 8192ull * 768 * 2;        // bf16 7077888
static constexpr size_t OFF_LSE = OFF_W + 7077888ull * 2;           // f32 192*512
static constexpr size_t OFF_SV = OFF_LSE + 192ull * 512 * 4;        // f32 192*64
static constexpr size_t OFF_M = OFF_SV + 192ull * 64 * 4;           // f32 192*64*64
static constexpr size_t WS_NEED = OFF_M + 192ull * 64 * 64 * 4;

extern "C" void kernel_launch(void* const* d_in, const int* in_sizes, int n_in,
                              void* d_out, int out_size, void* d_ws,
                              size_t ws_size, hipStream_t stream) {
  const int* ids = (const int*)d_in[0];
  const float* tok = (const float*)d_in[1];
  const float* pos = (const float*)d_in[2];
  const float* eln_s = (const float*)d_in[3];
  const float* eln_b = (const float*)d_in[4];
  const float* wq = (const float*)d_in[5];
  const float* wk = (const float*)d_in[6];
  const float* wv = (const float*)d_in[7];
  const float* wo = (const float*)d_in[8];
  const float* wo_b = (const float*)d_in[9];
  const float* ln1_s = (const float*)d_in[10];
  const float* ln1_b = (const float*)d_in[11];
  const float* ln2_s = (const float*)d_in[12];
  const float* ln2_b = (const float*)d_in[13];
  const float* ff1w = (const float*)d_in[14];
  const float* ff1b = (const float*)d_in[15];
  const float* ff2w = (const float*)d_in[16];
  const float* ff2b = (const float*)d_in[17];
  const float* fln_s = (const float*)d_in[18];
  const float* fln_b = (const float*)d_in[19];
  const float* cw = (const float*)d_in[20];
  const float* cb = (const float*)d_in[21];
  float* out = (float*)d_out;

  if (ws_size < WS_NEED) return;  // workspace too small; will fail validation loudly

  char* ws = (char*)d_ws;
  float* x = (float*)(ws + OFF_X);
  bf16_t* h = (bf16_t*)(ws + OFF_H);
  bf16_t* qkv = (bf16_t*)(ws + OFF_QG);
  bf16_t* gbuf = (bf16_t*)(ws + OFF_QG);
  bf16_t* ctx = (bf16_t*)(ws + OFF_CTX);
  bf16_t* wT = (bf16_t*)(ws + OFF_W);
  float* lseb = (float*)(ws + OFF_LSE);
  float* sv = (float*)(ws + OFF_SV);
  float* Mb = (float*)(ws + OFF_M);

  bf16_t* qkvT = wT;                  // [2304][768]
  bf16_t* woT = wT + 1769472;         // [768][768]
  bf16_t* ff1T = wT + 2359296;        // [3072][768]
  bf16_t* ff2T = wT + 4718592;        // [768][3072]

  k_embed<<<8192, 192, 0, stream>>>(ids, tok, pos, eln_s, eln_b, x);

  for (int l = 0; l < 12; ++l) {
    k_ln<<<8192, 192, 0, stream>>>(x, h, ln1_s + l * 768, ln1_b + l * 768);
    // weight convert+transpose (per layer, reused buffers)
    k_convT<<<dim3(2, 24, 12), 256, 0, stream>>>(wq + (size_t)l * 12 * 768 * 64,
                                                 768 * 64, qkvT, (size_t)64 * 768, 64, 768);
    k_convT<<<dim3(2, 24, 12), 256, 0, stream>>>(wk + (size_t)l * 12 * 768 * 64,
                                                 768 * 64, qkvT + 768 * 768, (size_t)64 * 768, 64, 768);
    k_convT<<<dim3(2, 24, 12), 256, 0, stream>>>(wv + (size_t)l * 12 * 768 * 64,
                                                 768 * 64, qkvT + 1536 * 768, (size_t)64 * 768, 64, 768);
    k_convT<<<dim3(24, 24, 1), 256, 0, stream>>>(wo + (size_t)l * 768 * 768, 0,
                                                 woT, 0, 768, 768);
    k_convT<<<dim3(96, 24, 1), 256, 0, stream>>>(ff1w + (size_t)l * 768 * 3072, 0,
                                                 ff1T, 0, 3072, 768);
    k_convT<<<dim3(24, 96, 1), 256, 0, stream>>>(ff2w + (size_t)l * 3072 * 768, 0,
                                                 ff2T, 0, 768, 3072);
    // QKV projection
    k_gemm<0><<<dim3(18, 64), 256, 0, stream>>>(h, 768, qkvT, 768, 768, nullptr,
                                                qkv, 2304, nullptr);
    // attention (log-softmax decomposition)
    k_lse<<<dim3(192, 8), 256, 0, stream>>>(qkv, lseb);
    k_msumv<<<192, 256, 0, stream>>>(qkv, Mb, sv);
    k_ctx<<<192, 256, 0, stream>>>(qkv, Mb, sv, lseb, ctx);
    // output projection + residual
    k_gemm<1><<<dim3(6, 64), 256, 0, stream>>>(ctx, 768, woT, 768, 768, x,
                                               nullptr, 768, wo_b + l * 768);
    // FFN
    k_ln<<<8192, 192, 0, stream>>>(x, h, ln2_s + l * 768, ln2_b + l * 768);
    k_gemm<2><<<dim3(24, 64), 256, 0, stream>>>(h, 768, ff1T, 768, 768, nullptr,
                                                gbuf, 3072, ff1b + l * 3072);
    k_gemm<1><<<dim3(6, 64), 256, 0, stream>>>(gbuf, 3072, ff2T, 3072, 3072, x,
                                               nullptr, 768, ff2b + l * 768);
  }
  k_final<<<16, 192, 0, stream>>>(x, fln_s, fln_b, cw, cb, out);
}